// Round 12
// baseline (455.031 us; speedup 1.0000x reference)
//
#include <hip/hip_runtime.h>

#define WS 9
#define PS 7
#define KMAX 10
#define STRIDE0 4
#define NEPOCHS 100
#define BB 1
#define TT 5
#define CC 3
#define HH 256
#define WW 256
#define QQ (TT * 64 * 64)             // 20480
#define NOFF 243
#define SELF_IDX 40                   // (WS/2)*WS + WS/2
#define HW (HH * WW)
#define TSTR 20                       // tile row stride: 80B = b128-aligned

typedef float f4a __attribute__((ext_vector_type(4)));              // aligned LDS/reg
typedef float f4u __attribute__((ext_vector_type(4), aligned(4)));  // 4B-aligned global

static __device__ __forceinline__ int k_eff_from_epoch(int ep) {
    int k = (int)((double)KMAX * ((double)(NEPOCHS - ep) / (double)NEPOCHS));
    return k < 2 ? 2 : k;
}

template <int CTRL>
static __device__ __forceinline__ float dpp_add(float v) {
    const int x = __float_as_int(v);
    const int y = __builtin_amdgcn_update_dpp(0, x, CTRL, 0xF, 0xF, true);
    return v + __int_as_float(y);
}
static __device__ __forceinline__ float swz4_add(float v) {
    const int x = __float_as_int(v);
    const int y = __builtin_amdgcn_ds_swizzle(x, 0x101F);   // xor-4, and=0x1F
    return v + __int_as_float(y);
}

// TWO queries per 512-thread block, side-by-side: half = tid>>8 picks the
// query and its LDS buffer; each half is the R10 pipeline verbatim (bit-exact
// per-query instruction stream). Halves run in parallel (no serialization);
// block count halves -> tests the dispatch-rate cap cleanly. Block-wide
// barriers cover both halves. After the post-search barrier, wave 0 of each
// half does top-k + refine; the other 6 waves exit.
__global__ __launch_bounds__(512) void dnls_query_kernel(
    const float* __restrict__ noisy, const float* __restrict__ deno,
    const float* __restrict__ fflow, const float* __restrict__ bflow,
    const int* __restrict__ ep_ptr, float* __restrict__ partial)
{
    const int tid  = threadIdx.x;
    const int half = tid >> 8;          // query slot within the block
    const int t    = tid & 255;         // local tid within the half
    const int lane = tid & 63;
    const int q    = blockIdx.x * 2 + half;
    const int tqi  = q >> 12;
    const int r0   = q & 4095;
    const int hq   = (r0 >> 6) * STRIDE0;
    const int wq   = (r0 & 63) * STRIDE0;
    const int k_eff = k_eff_from_epoch(ep_ptr[0]);

    __shared__ __align__(16) float tile[2][3][CC][15][TSTR];   // 21.6 KB
    __shared__ float dpat[2][CC][PS][8];                       // deno query patches
    __shared__ float dists[2][256];

    // --- centers (every thread; flow loads are wave-uniform -> broadcast) ---
    const size_t bfo = (size_t)(tqi * 2) * HW + (size_t)hq * WW + wq;
    const int ifdx = (int)rintf(fflow[bfo]);
    const int ifdy = (int)rintf(fflow[bfo + HW]);
    const int ibdx = (int)rintf(bflow[bfo]);
    const int ibdy = (int)rintf(bflow[bfo + HW]);
    const int tc0 = tqi, tc1 = max(tqi - 1, 0), tc2 = min(tqi + 1, TT - 1);
    const int hv0 = hq, hv1 = min(max(hq + ibdy, 0), HH - 1), hv2 = min(max(hq + ifdy, 0), HH - 1);
    const int wv0 = wq, wv1 = min(max(wq + ibdx, 0), WW - 1), wv2 = min(max(wq + ifdx, 0), WW - 1);

    // --- staging: half-uniform interior test ---
    const bool allint = (hv0 <= HH - 11) & (wv0 <= WW - 12) &
                        (hv1 <= HH - 11) & (wv1 <= WW - 12) &
                        (hv2 <= HH - 11) & (wv2 <= WW - 12);
    if (allint) {
        // vectorized: 540 b128 quads (plane p=(dti,c), row, quad), zero clamps
        #pragma unroll
        for (int rr = 0; rr < 3; ++rr) {
            const int u = t + rr * 256;
            if (u < 540) {
                const int p   = u / 60;
                const int rem = u - p * 60;
                const int row = rem >> 2, qd = rem & 3;
                const int dti = (p >= 6) ? 2 : (p >= 3 ? 1 : 0);
                const int c   = p - dti * 3;
                const int tcv = dti == 0 ? tc0 : (dti == 1 ? tc1 : tc2);
                const int hcv = dti == 0 ? hv0 : (dti == 1 ? hv1 : hv2);
                const int wcv = dti == 0 ? wv0 : (dti == 1 ? wv1 : wv2);
                const int h0  = max(hcv - 4, 0), w0 = max(wcv - 4, 0);
                const float* src = noisy + (size_t)(tcv * CC + c) * HW;
                *(f4a*)&tile[half][dti][c][row][qd * 4] =
                    (f4a)(*(const f4u*)(src + (h0 + row) * WW + w0 + qd * 4));
            }
        }
    } else {
        // scalar per-plane path: clamps baked in, uniform branch per plane
        #pragma unroll
        for (int dtc = 0; dtc < 9; ++dtc) {
            const int dti = dtc / 3, c = dtc % 3;          // compile-time
            if (t < 225) {
                const int row = t / 15;
                const int col = t - row * 15;
                const int tcv = dti == 0 ? tc0 : (dti == 1 ? tc1 : tc2);
                const int hcv = dti == 0 ? hv0 : (dti == 1 ? hv1 : hv2);
                const int wcv = dti == 0 ? wv0 : (dti == 1 ? wv1 : wv2);
                const int h0 = max(hcv - 4, 0), w0 = max(wcv - 4, 0);
                const float* src = noisy + (size_t)(tcv * CC + c) * HW;
                tile[half][dti][c][row][col] =
                    src[min(h0 + row, HH - 1) * WW + min(w0 + col, WW - 1)];
            }
        }
    }
    // --- stage deno query patch (clamps baked in) ---
    if (t < CC * PS * PS) {
        const int c = t / 49, ij = t - c * 49, i = ij / 7, j = ij - (ij / 7) * 7;
        dpat[half][c][i][j] = deno[(size_t)(tqi * CC + c) * HW
                              + min(hq + i, HH - 1) * WW + min(wq + j, WW - 1)];
    }
    __syncthreads();

    // --- search: group g=(dti,dh), sub = patch row i (sub==7 idle) ---
    {
        const int g = t >> 3, sub = t & 7;
        if (g < 27) {
            const int dti = (g >= 18) ? 2 : (g >= 9 ? 1 : 0);
            const int dh  = g - 9 * dti;
            const int hcv = dti == 0 ? hv0 : (dti == 1 ? hv1 : hv2);
            const int wcv = dti == 0 ? wv0 : (dti == 1 ? wv1 : wv2);
            float acc[9];
            #pragma unroll
            for (int dw = 0; dw < 9; ++dw) acc[dw] = 0.f;
            if (sub < PS) {
                const int i  = sub;
                const int oh = min(hq, 4), ow = min(wq, 4);   // query patch in tile[half][0]
                float qv[CC][8];
                #pragma unroll
                for (int c = 0; c < CC; ++c) {
                    *(f4a*)&qv[c][0] = *(const f4a*)&tile[half][0][c][oh + i][ow];
                    *(f4a*)&qv[c][4] = *(const f4a*)&tile[half][0][c][oh + i][ow + 4];
                }
                if (hcv >= 4 && wcv >= 4) {
                    // fast path: staged clamps are exact; r = dh+i, cols = dw+j
                    const int r = dh + i;
                    #pragma unroll
                    for (int c = 0; c < CC; ++c) {
                        float tv[16];
                        *(f4a*)&tv[0]  = *(const f4a*)&tile[half][dti][c][r][0];
                        *(f4a*)&tv[4]  = *(const f4a*)&tile[half][dti][c][r][4];
                        *(f4a*)&tv[8]  = *(const f4a*)&tile[half][dti][c][r][8];
                        *(f4a*)&tv[12] = *(const f4a*)&tile[half][dti][c][r][12];
                        #pragma unroll
                        for (int dw = 0; dw < 9; ++dw) {
                            #pragma unroll
                            for (int j = 0; j < 7; ++j) {
                                const float d = qv[c][j] - tv[dw + j];
                                acc[dw] = fmaf(d, d, acc[dw]);
                            }
                        }
                    }
                } else {
                    // top/left-edge centers: double clamp mapped into the tile
                    const int h0 = max(hcv - 4, 0), w0 = max(wcv - 4, 0);
                    const int hc = min(max(hcv + dh - 4, 0), HH - 1);
                    const int r  = min(hc + i, HH - 1) - h0;
                    #pragma unroll
                    for (int c = 0; c < CC; ++c) {
                        #pragma unroll
                        for (int dw = 0; dw < 9; ++dw) {
                            const int wc = min(max(wcv + dw - 4, 0), WW - 1);
                            #pragma unroll
                            for (int j = 0; j < 7; ++j) {
                                const int col = min(wc + j, WW - 1) - w0;
                                const float d = qv[c][j] - tile[half][dti][c][r][col];
                                acc[dw] = fmaf(d, d, acc[dw]);
                            }
                        }
                    }
                }
            }
            // sum the 7 rows across the 8-lane segment (same tree as __shfl_xor)
            #pragma unroll
            for (int dw = 0; dw < 9; ++dw) {
                float v = acc[dw];
                v = dpp_add<0xB1>(v);   // quad_perm [1,0,3,2] : xor 1
                v = dpp_add<0x4E>(v);   // quad_perm [2,3,0,1] : xor 2
                v = swz4_add(v);        // xor 4 within 8-lane group
                acc[dw] = v;
            }
            if (sub == 0) {
                #pragma unroll
                for (int dw = 0; dw < 9; ++dw) dists[half][g * 9 + dw] = acc[dw];
            }
        }
    }
    __syncthreads();

    if (t >= 64) return;   // 6 of 8 waves done; wave 0 of each half finishes

    // --- in-register top-k (strict <, lowest-index tie-break) ---
    const float* dq = dists[half];
    float dv[4]; int dn[4];
    #pragma unroll
    for (int kk = 0; kk < 4; ++kk) {
        const int n = lane + kk * 64;
        float v = (n < NOFF) ? dq[n] : INFINITY;
        if (n == SELF_IDX) v = -INFINITY;
        dv[kk] = v; dn[kk] = n;
    }
    int seln[KMAX];
    #pragma unroll
    for (int k = 0; k < KMAX; ++k) {
        float bv = dv[0]; int bi = dn[0];
        #pragma unroll
        for (int kk = 1; kk < 4; ++kk)
            if (dv[kk] < bv || (dv[kk] == bv && dn[kk] < bi)) { bv = dv[kk]; bi = dn[kk]; }
        #pragma unroll
        for (int off = 32; off > 0; off >>= 1) {
            const float ov = __shfl_xor(bv, off);
            const int   oi = __shfl_xor(bi, off);
            if (ov < bv || (ov == bv && oi < bi)) { bv = ov; bi = oi; }
        }
        seln[k] = bi;
        #pragma unroll
        for (int kk = 0; kk < 4; ++kk) if (dn[kk] == bi) dv[kk] = INFINITY;
    }

    // --- refine: deno-query vs noisy at selected positions (slots 1..k_eff-1) ---
    float part = 0.f;
    const int nref = (k_eff - 1) * 49;
    for (int u = lane; u < nref; u += 64) {
        const int kk = u / 49 + 1;
        const int ij = u - (kk - 1) * 49;
        const int i = ij / 7, j = ij - (ij / 7) * 7;
        int n = seln[1];
        #pragma unroll
        for (int tt = 2; tt < KMAX; ++tt) if (kk == tt) n = seln[tt];
        const int dti = (n >= 162) ? 2 : (n >= 81 ? 1 : 0);
        const int rr  = n - dti * 81;
        const int dh  = rr / 9;
        const int dw  = rr - dh * 9;
        const int hcv = dti == 0 ? hv0 : (dti == 1 ? hv1 : hv2);
        const int wcv = dti == 0 ? wv0 : (dti == 1 ? wv1 : wv2);
        const int h0  = max(hcv - 4, 0), w0 = max(wcv - 4, 0);
        const int hc  = min(max(hcv + dh - 4, 0), HH - 1);
        const int wc  = min(max(wcv + dw - 4, 0), WW - 1);
        const int row = min(hc + i, HH - 1) - h0;
        const int col = min(wc + j, WW - 1) - w0;
        #pragma unroll
        for (int c = 0; c < CC; ++c) {
            const float d = dpat[half][c][i][j] - tile[half][dti][c][row][col];
            part = fmaf(d, d, part);
        }
    }

    #pragma unroll
    for (int off = 32; off > 0; off >>= 1) part += __shfl_xor(part, off);
    if (lane == 0) partial[q] = part;
}

__global__ __launch_bounds__(1024) void dnls_reduce_kernel(
    const float* __restrict__ partial, int n,
    const int* __restrict__ ep_ptr, float* __restrict__ out)
{
    const int tid = threadIdx.x;
    double acc = 0.0;
    for (int i = tid; i < n; i += 1024) acc += (double)partial[i];
    __shared__ double red[1024];
    red[tid] = acc;
    __syncthreads();
    for (int s = 512; s > 0; s >>= 1) {
        if (tid < s) red[tid] += red[tid + s];
        __syncthreads();
    }
    if (tid == 0) {
        const int k_eff = k_eff_from_epoch(ep_ptr[0]);
        out[0] = (float)(red[0] / ((double)n * (double)(k_eff - 1)));
    }
}

extern "C" void kernel_launch(void* const* d_in, const int* in_sizes, int n_in,
                              void* d_out, int out_size, void* d_ws, size_t ws_size,
                              hipStream_t stream) {
    const float* noisy = (const float*)d_in[0];
    const float* deno  = (const float*)d_in[1];
    const float* fflow = (const float*)d_in[2];
    const float* bflow = (const float*)d_in[3];
    const int*   ep    = (const int*)d_in[4];
    float* partial = (float*)d_ws;            // BB*QQ floats = 80 KB
    float* out = (float*)d_out;

    dnls_query_kernel<<<(BB * QQ) / 2, 512, 0, stream>>>(noisy, deno, fflow, bflow, ep, partial);
    dnls_reduce_kernel<<<1, 1024, 0, stream>>>(partial, BB * QQ, ep, out);
}

// Round 13
// 209.513 us; speedup vs baseline: 2.1718x; 2.1718x over previous
//
#include <hip/hip_runtime.h>

#define WS 9
#define PS 7
#define KMAX 10
#define STRIDE0 4
#define NEPOCHS 100
#define BB 1
#define TT 5
#define CC 3
#define HH 256
#define WW 256
#define QQ (TT * 64 * 64)             // 20480
#define NOFF 243
#define SELF_IDX 40                   // (WS/2)*WS + WS/2
#define HW (HH * WW)
#define TSTR 20                       // tile row stride: 80B = b128-aligned

typedef float f4a __attribute__((ext_vector_type(4)));              // aligned LDS/reg
typedef float f4u __attribute__((ext_vector_type(4), aligned(4)));  // 4B-aligned global

static __device__ __forceinline__ int k_eff_from_epoch(int ep) {
    int k = (int)((double)KMAX * ((double)(NEPOCHS - ep) / (double)NEPOCHS));
    return k < 2 ? 2 : k;
}

template <int CTRL>
static __device__ __forceinline__ float dpp_add(float v) {
    const int x = __float_as_int(v);
    const int y = __builtin_amdgcn_update_dpp(0, x, CTRL, 0xF, 0xF, true);
    return v + __int_as_float(y);
}
static __device__ __forceinline__ float swz4_add(float v) {
    const int x = __float_as_int(v);
    const int y = __builtin_amdgcn_ds_swizzle(x, 0x101F);   // xor-4, and=0x1F
    return v + __int_as_float(y);
}

// One query per 256-thread block (R10 skeleton) with FUSED REFINE: the search
// phase slides BOTH the noisy query row (qv, for selection dists — bit-exact
// vs R10) and the deno query row (dqv, for refine dists) against the same tv
// registers, writing dists[] and rdists[] for all 243 candidates. The wave-0
// tail is then just top-k + sum of rdists[seln[1..k_eff-1]] (9 broadcast LDS
// reads) — the serial refine chain is gone. Waves 1-3 exit after barrier 2.
__global__ __launch_bounds__(256) void dnls_query_kernel(
    const float* __restrict__ noisy, const float* __restrict__ deno,
    const float* __restrict__ fflow, const float* __restrict__ bflow,
    const int* __restrict__ ep_ptr, float* __restrict__ partial)
{
    const int q    = blockIdx.x;
    const int tqi  = q >> 12;
    const int r0   = q & 4095;
    const int hq   = (r0 >> 6) * STRIDE0;
    const int wq   = (r0 & 63) * STRIDE0;
    const int tid  = threadIdx.x;
    const int lane = tid & 63;
    const int k_eff = k_eff_from_epoch(ep_ptr[0]);

    __shared__ __align__(16) float tile[3][CC][15][TSTR];   // 10.8 KB
    __shared__ float dpat[CC][PS][8];                       // deno query patch
    __shared__ float dists[256];                            // selection dists
    __shared__ float rdists[256];                           // refine dists

    // --- centers (every thread; flow loads are wave-uniform -> broadcast) ---
    const size_t bfo = (size_t)(tqi * 2) * HW + (size_t)hq * WW + wq;
    const int ifdx = (int)rintf(fflow[bfo]);
    const int ifdy = (int)rintf(fflow[bfo + HW]);
    const int ibdx = (int)rintf(bflow[bfo]);
    const int ibdy = (int)rintf(bflow[bfo + HW]);
    const int tc0 = tqi, tc1 = max(tqi - 1, 0), tc2 = min(tqi + 1, TT - 1);
    const int hv0 = hq, hv1 = min(max(hq + ibdy, 0), HH - 1), hv2 = min(max(hq + ifdy, 0), HH - 1);
    const int wv0 = wq, wv1 = min(max(wq + ibdx, 0), WW - 1), wv2 = min(max(wq + ifdx, 0), WW - 1);

    // --- staging: block-uniform interior test ---
    const bool allint = (hv0 <= HH - 11) & (wv0 <= WW - 12) &
                        (hv1 <= HH - 11) & (wv1 <= WW - 12) &
                        (hv2 <= HH - 11) & (wv2 <= WW - 12);
    if (allint) {
        // vectorized: 540 b128 quads (plane p=(dti,c), row, quad), zero clamps
        #pragma unroll
        for (int rr = 0; rr < 3; ++rr) {
            const int u = tid + rr * 256;
            if (u < 540) {
                const int p   = u / 60;
                const int rem = u - p * 60;
                const int row = rem >> 2, qd = rem & 3;
                const int dti = (p >= 6) ? 2 : (p >= 3 ? 1 : 0);
                const int c   = p - dti * 3;
                const int tcv = dti == 0 ? tc0 : (dti == 1 ? tc1 : tc2);
                const int hcv = dti == 0 ? hv0 : (dti == 1 ? hv1 : hv2);
                const int wcv = dti == 0 ? wv0 : (dti == 1 ? wv1 : wv2);
                const int h0  = max(hcv - 4, 0), w0 = max(wcv - 4, 0);
                const float* src = noisy + (size_t)(tcv * CC + c) * HW;
                *(f4a*)&tile[dti][c][row][qd * 4] =
                    (f4a)(*(const f4u*)(src + (h0 + row) * WW + w0 + qd * 4));
            }
        }
    } else {
        // scalar per-plane path: clamps baked in, uniform branch per plane
        #pragma unroll
        for (int dtc = 0; dtc < 9; ++dtc) {
            const int dti = dtc / 3, c = dtc % 3;          // compile-time
            if (tid < 225) {
                const int row = tid / 15;
                const int col = tid - row * 15;
                const int tcv = dti == 0 ? tc0 : (dti == 1 ? tc1 : tc2);
                const int hcv = dti == 0 ? hv0 : (dti == 1 ? hv1 : hv2);
                const int wcv = dti == 0 ? wv0 : (dti == 1 ? wv1 : wv2);
                const int h0 = max(hcv - 4, 0), w0 = max(wcv - 4, 0);
                const float* src = noisy + (size_t)(tcv * CC + c) * HW;
                tile[dti][c][row][col] =
                    src[min(h0 + row, HH - 1) * WW + min(w0 + col, WW - 1)];
            }
        }
    }
    // --- stage deno query patch (clamps baked in) ---
    if (tid < CC * PS * PS) {
        const int c = tid / 49, ij = tid - c * 49, i = ij / 7, j = ij - (ij / 7) * 7;
        dpat[c][i][j] = deno[(size_t)(tqi * CC + c) * HW
                             + min(hq + i, HH - 1) * WW + min(wq + j, WW - 1)];
    }
    __syncthreads();

    // --- fused search+refine: group g=(dti,dh), sub = patch row i (7 idle) ---
    {
        const int g = tid >> 3, sub = tid & 7;
        if (g < 27) {
            const int dti = (g >= 18) ? 2 : (g >= 9 ? 1 : 0);
            const int dh  = g - 9 * dti;
            const int hcv = dti == 0 ? hv0 : (dti == 1 ? hv1 : hv2);
            const int wcv = dti == 0 ? wv0 : (dti == 1 ? wv1 : wv2);
            float acc[9], racc[9];
            #pragma unroll
            for (int dw = 0; dw < 9; ++dw) { acc[dw] = 0.f; racc[dw] = 0.f; }
            if (sub < PS) {
                const int i  = sub;
                const int oh = min(hq, 4), ow = min(wq, 4);   // query patch inside tile[0]
                float qv[CC][8], dqv[CC][8];
                #pragma unroll
                for (int c = 0; c < CC; ++c) {
                    *(f4a*)&qv[c][0]  = *(const f4a*)&tile[0][c][oh + i][ow];
                    *(f4a*)&qv[c][4]  = *(const f4a*)&tile[0][c][oh + i][ow + 4];
                    *(f4a*)&dqv[c][0] = *(const f4a*)&dpat[c][i][0];
                    *(f4a*)&dqv[c][4] = *(const f4a*)&dpat[c][i][4];
                }
                if (hcv >= 4 && wcv >= 4) {
                    // fast path: staged clamps are exact; r = dh+i, cols = dw+j
                    const int r = dh + i;
                    #pragma unroll
                    for (int c = 0; c < CC; ++c) {
                        float tv[16];
                        *(f4a*)&tv[0]  = *(const f4a*)&tile[dti][c][r][0];
                        *(f4a*)&tv[4]  = *(const f4a*)&tile[dti][c][r][4];
                        *(f4a*)&tv[8]  = *(const f4a*)&tile[dti][c][r][8];
                        *(f4a*)&tv[12] = *(const f4a*)&tile[dti][c][r][12];
                        #pragma unroll
                        for (int dw = 0; dw < 9; ++dw) {
                            #pragma unroll
                            for (int j = 0; j < 7; ++j) {
                                const float d  = qv[c][j]  - tv[dw + j];
                                const float rd = dqv[c][j] - tv[dw + j];
                                acc[dw]  = fmaf(d, d, acc[dw]);
                                racc[dw] = fmaf(rd, rd, racc[dw]);
                            }
                        }
                    }
                } else {
                    // top/left-edge centers: double clamp mapped into the tile
                    const int h0 = max(hcv - 4, 0), w0 = max(wcv - 4, 0);
                    const int hc = min(max(hcv + dh - 4, 0), HH - 1);
                    const int r  = min(hc + i, HH - 1) - h0;
                    #pragma unroll
                    for (int c = 0; c < CC; ++c) {
                        #pragma unroll
                        for (int dw = 0; dw < 9; ++dw) {
                            const int wc = min(max(wcv + dw - 4, 0), WW - 1);
                            #pragma unroll
                            for (int j = 0; j < 7; ++j) {
                                const int col = min(wc + j, WW - 1) - w0;
                                const float tvv = tile[dti][c][r][col];
                                const float d  = qv[c][j]  - tvv;
                                const float rd = dqv[c][j] - tvv;
                                acc[dw]  = fmaf(d, d, acc[dw]);
                                racc[dw] = fmaf(rd, rd, racc[dw]);
                            }
                        }
                    }
                }
            }
            // sum the 7 rows across the 8-lane segment (same tree as __shfl_xor)
            #pragma unroll
            for (int dw = 0; dw < 9; ++dw) {
                float v = acc[dw];
                v = dpp_add<0xB1>(v);   // quad_perm [1,0,3,2] : xor 1
                v = dpp_add<0x4E>(v);   // quad_perm [2,3,0,1] : xor 2
                v = swz4_add(v);        // xor 4 within 8-lane group
                acc[dw] = v;
                float rv = racc[dw];
                rv = dpp_add<0xB1>(rv);
                rv = dpp_add<0x4E>(rv);
                rv = swz4_add(rv);
                racc[dw] = rv;
            }
            if (sub == 0) {
                #pragma unroll
                for (int dw = 0; dw < 9; ++dw) {
                    dists[g * 9 + dw]  = acc[dw];
                    rdists[g * 9 + dw] = racc[dw];
                }
            }
        }
    }
    __syncthreads();

    if (tid >= 64) return;   // waves 1-3 done; wave 0 finishes the query

    // --- in-register top-k, wave 0 only (strict <, lowest-index tie-break) ---
    float dv[4]; int dn[4];
    #pragma unroll
    for (int kk = 0; kk < 4; ++kk) {
        const int n = lane + kk * 64;
        float v = (n < NOFF) ? dists[n] : INFINITY;
        if (n == SELF_IDX) v = -INFINITY;
        dv[kk] = v; dn[kk] = n;
    }
    int seln[KMAX];
    #pragma unroll
    for (int k = 0; k < KMAX; ++k) {
        float bv = dv[0]; int bi = dn[0];
        #pragma unroll
        for (int kk = 1; kk < 4; ++kk)
            if (dv[kk] < bv || (dv[kk] == bv && dn[kk] < bi)) { bv = dv[kk]; bi = dn[kk]; }
        #pragma unroll
        for (int off = 32; off > 0; off >>= 1) {
            const float ov = __shfl_xor(bv, off);
            const int   oi = __shfl_xor(bi, off);
            if (ov < bv || (ov == bv && oi < bi)) { bv = ov; bi = oi; }
        }
        seln[k] = bi;
        #pragma unroll
        for (int kk = 0; kk < 4; ++kk) if (dn[kk] == bi) dv[kk] = INFINITY;
    }

    // --- refine result: sum precomputed rdists at slots 1..k_eff-1 ---
    float part = 0.f;
    #pragma unroll
    for (int k = 1; k < KMAX; ++k)
        if (k < k_eff) part += rdists[seln[k]];   // uniform broadcast reads
    if (lane == 0) partial[q] = part;
}

__global__ __launch_bounds__(1024) void dnls_reduce_kernel(
    const float* __restrict__ partial, int n,
    const int* __restrict__ ep_ptr, float* __restrict__ out)
{
    const int tid = threadIdx.x;
    double acc = 0.0;
    for (int i = tid; i < n; i += 1024) acc += (double)partial[i];
    __shared__ double red[1024];
    red[tid] = acc;
    __syncthreads();
    for (int s = 512; s > 0; s >>= 1) {
        if (tid < s) red[tid] += red[tid + s];
        __syncthreads();
    }
    if (tid == 0) {
        const int k_eff = k_eff_from_epoch(ep_ptr[0]);
        out[0] = (float)(red[0] / ((double)n * (double)(k_eff - 1)));
    }
}

extern "C" void kernel_launch(void* const* d_in, const int* in_sizes, int n_in,
                              void* d_out, int out_size, void* d_ws, size_t ws_size,
                              hipStream_t stream) {
    const float* noisy = (const float*)d_in[0];
    const float* deno  = (const float*)d_in[1];
    const float* fflow = (const float*)d_in[2];
    const float* bflow = (const float*)d_in[3];
    const int*   ep    = (const int*)d_in[4];
    float* partial = (float*)d_ws;            // BB*QQ floats = 80 KB
    float* out = (float*)d_out;

    dnls_query_kernel<<<BB * QQ, 256, 0, stream>>>(noisy, deno, fflow, bflow, ep, partial);
    dnls_reduce_kernel<<<1, 1024, 0, stream>>>(partial, BB * QQ, ep, out);
}

// Round 14
// 137.951 us; speedup vs baseline: 3.2985x; 1.5188x over previous
//
#include <hip/hip_runtime.h>

#define WS 9
#define PS 7
#define KMAX 10
#define STRIDE0 4
#define NEPOCHS 100
#define BB 1
#define TT 5
#define CC 3
#define HH 256
#define WW 256
#define QQ (TT * 64 * 64)             // 20480
#define NOFF 243
#define SELF_IDX 40                   // (WS/2)*WS + WS/2
#define HW (HH * WW)
#define TSTR 20                       // tile row stride: 80B = b128-aligned

typedef float f4a __attribute__((ext_vector_type(4)));              // aligned LDS/reg
typedef float f4u __attribute__((ext_vector_type(4), aligned(4)));  // 4B-aligned global

static __device__ __forceinline__ int k_eff_from_epoch(int ep) {
    int k = (int)((double)KMAX * ((double)(NEPOCHS - ep) / (double)NEPOCHS));
    return k < 2 ? 2 : k;
}

template <int CTRL>
static __device__ __forceinline__ float dpp_add(float v) {
    const int x = __float_as_int(v);
    const int y = __builtin_amdgcn_update_dpp(0, x, CTRL, 0xF, 0xF, true);
    return v + __int_as_float(y);
}
static __device__ __forceinline__ float swz4_add(float v) {
    const int x = __float_as_int(v);
    const int y = __builtin_amdgcn_ds_swizzle(x, 0x101F);   // xor-4, and=0x1F
    return v + __int_as_float(y);
}

// 4 fully independent WAVE-LOCAL queries per 256-thread block; ZERO
// __syncthreads. Per wave: stage own 10.8KB tile (9 unrolled dwordx4+
// ds_write_b128 rounds, all loads independent -> pipelined), stage dpat,
// wave_barrier (in-order DS pipe gives RAW ordering), qv hoisted once from
// tile[0] (R7 bit-exact trick), search = 4 iterations x 8 groups (R6 scheme,
// R7 math), in-register top-k, R7 refine. Selection bit-exact vs R7.
__global__ __launch_bounds__(256) void dnls_query_kernel(
    const float* __restrict__ noisy, const float* __restrict__ deno,
    const float* __restrict__ fflow, const float* __restrict__ bflow,
    const int* __restrict__ ep_ptr, float* __restrict__ partial)
{
    const int tid  = threadIdx.x;
    const int wid  = tid >> 6;
    const int lane = tid & 63;
    const int sub  = lane & 7;
    const int q    = blockIdx.x * 4 + wid;
    const int tqi  = q >> 12;
    const int r0   = q & 4095;
    const int hq   = (r0 >> 6) * STRIDE0;
    const int wq   = (r0 & 63) * STRIDE0;
    const int k_eff = k_eff_from_epoch(ep_ptr[0]);

    __shared__ __align__(16) float tile[4][3][CC][15][TSTR];   // 43.2 KB
    __shared__ float dpat[4][CC][PS][8];                       // 2.7 KB
    __shared__ float dists[4][256];                            // 4 KB

    // --- centers (wave-uniform; flow loads broadcast) ---
    const size_t bfo = (size_t)(tqi * 2) * HW + (size_t)hq * WW + wq;
    const int ifdx = (int)rintf(fflow[bfo]);
    const int ifdy = (int)rintf(fflow[bfo + HW]);
    const int ibdx = (int)rintf(bflow[bfo]);
    const int ibdy = (int)rintf(bflow[bfo + HW]);
    const int tc0 = tqi, tc1 = max(tqi - 1, 0), tc2 = min(tqi + 1, TT - 1);
    const int hv0 = hq, hv1 = min(max(hq + ibdy, 0), HH - 1), hv2 = min(max(hq + ifdy, 0), HH - 1);
    const int wv0 = wq, wv1 = min(max(wq + ibdx, 0), WW - 1), wv2 = min(max(wq + ifdx, 0), WW - 1);

    // --- per-wave tile staging: 540 b128 quads over 64 lanes, 9 rounds ---
    #pragma unroll
    for (int rr = 0; rr < 9; ++rr) {
        const int u = lane + rr * 64;
        if (u < 540) {
            const int p   = u / 60;
            const int rem = u - p * 60;
            const int row = rem >> 2, qd = rem & 3;
            const int dti = (p >= 6) ? 2 : (p >= 3 ? 1 : 0);
            const int c   = p - dti * 3;
            const int tcv = dti == 0 ? tc0 : (dti == 1 ? tc1 : tc2);
            const int hcv = dti == 0 ? hv0 : (dti == 1 ? hv1 : hv2);
            const int wcv = dti == 0 ? wv0 : (dti == 1 ? wv1 : wv2);
            const int h0  = max(hcv - 4, 0), w0 = max(wcv - 4, 0);
            const float* src = noisy + (size_t)(tcv * CC + c) * HW;
            f4a v;
            if (hcv <= HH - 11 && wcv <= WW - 12) {
                v = (f4a)(*(const f4u*)(src + (h0 + row) * WW + w0 + qd * 4));
            } else {
                const int rrow = min(h0 + row, HH - 1);
                const float* sr = src + rrow * WW;
                #pragma unroll
                for (int t = 0; t < 4; ++t)
                    v[t] = sr[min(w0 + min(qd * 4 + t, 14), WW - 1)];
            }
            *(f4a*)&tile[wid][dti][c][row][qd * 4] = v;
        }
    }
    // --- per-wave dpat staging (clamps baked in) ---
    #pragma unroll
    for (int rr = 0; rr < 3; ++rr) {
        const int u = lane + rr * 64;
        if (u < CC * PS * PS) {
            const int c = u / 49, ij = u - c * 49, i = ij / 7, j = ij - (ij / 7) * 7;
            dpat[wid][c][i][j] = deno[(size_t)(tqi * CC + c) * HW
                                 + min(hq + i, HH - 1) * WW + min(wq + j, WW - 1)];
        }
    }
    __builtin_amdgcn_wave_barrier();   // order staging ds_writes before ds_reads

    // --- qv hoist: query patch row (i = sub) from tile[wid][0], bit-exact ---
    const int oh = min(hq, 4), ow = min(wq, 4);
    float qv[CC][8];
    #pragma unroll
    for (int c = 0; c < CC; ++c) {
        *(f4a*)&qv[c][0] = *(const f4a*)&tile[wid][0][c][oh + sub][ow];
        *(f4a*)&qv[c][4] = *(const f4a*)&tile[wid][0][c][oh + sub][ow + 4];
    }

    // --- search: 4 iterations x 8 groups; g=(dti,dh), lane sub = patch row i ---
    #pragma unroll
    for (int it = 0; it < 4; ++it) {
        const int g = it * 8 + (lane >> 3);
        if (g < 27) {
            const int dti = (g >= 18) ? 2 : (g >= 9 ? 1 : 0);
            const int dh  = g - 9 * dti;
            const int hcv = dti == 0 ? hv0 : (dti == 1 ? hv1 : hv2);
            const int wcv = dti == 0 ? wv0 : (dti == 1 ? wv1 : wv2);
            float acc[9];
            #pragma unroll
            for (int dw = 0; dw < 9; ++dw) acc[dw] = 0.f;
            if (sub < PS) {
                if (hcv >= 4 && wcv >= 4) {
                    // fast path: staged clamps exact; r = dh+i, cols = dw+j
                    const int r = dh + sub;
                    #pragma unroll
                    for (int c = 0; c < CC; ++c) {
                        float tv[16];
                        *(f4a*)&tv[0]  = *(const f4a*)&tile[wid][dti][c][r][0];
                        *(f4a*)&tv[4]  = *(const f4a*)&tile[wid][dti][c][r][4];
                        *(f4a*)&tv[8]  = *(const f4a*)&tile[wid][dti][c][r][8];
                        *(f4a*)&tv[12] = *(const f4a*)&tile[wid][dti][c][r][12];
                        #pragma unroll
                        for (int dw = 0; dw < 9; ++dw) {
                            #pragma unroll
                            for (int j = 0; j < 7; ++j) {
                                const float d = qv[c][j] - tv[dw + j];
                                acc[dw] = fmaf(d, d, acc[dw]);
                            }
                        }
                    }
                } else {
                    // top/left-edge centers: double clamp mapped into the tile
                    const int h0 = max(hcv - 4, 0), w0 = max(wcv - 4, 0);
                    const int hc = min(max(hcv + dh - 4, 0), HH - 1);
                    const int r  = min(hc + sub, HH - 1) - h0;
                    #pragma unroll
                    for (int c = 0; c < CC; ++c) {
                        #pragma unroll
                        for (int dw = 0; dw < 9; ++dw) {
                            const int wc = min(max(wcv + dw - 4, 0), WW - 1);
                            #pragma unroll
                            for (int j = 0; j < 7; ++j) {
                                const int col = min(wc + j, WW - 1) - w0;
                                const float d = qv[c][j] - tile[wid][dti][c][r][col];
                                acc[dw] = fmaf(d, d, acc[dw]);
                            }
                        }
                    }
                }
            }
            // sum the 7 rows across the 8-lane segment (same tree as __shfl_xor)
            #pragma unroll
            for (int dw = 0; dw < 9; ++dw) {
                float v = acc[dw];
                v = dpp_add<0xB1>(v);   // xor 1
                v = dpp_add<0x4E>(v);   // xor 2
                v = swz4_add(v);        // xor 4
                acc[dw] = v;
            }
            if (sub == 0) {
                #pragma unroll
                for (int dw = 0; dw < 9; ++dw) dists[wid][g * 9 + dw] = acc[dw];
            }
        }
    }
    __builtin_amdgcn_wave_barrier();   // order dist writes before reads

    // --- in-register top-k (strict <, lowest-index tie-break) ---
    const float* dq = dists[wid];
    float dv[4]; int dn[4];
    #pragma unroll
    for (int kk = 0; kk < 4; ++kk) {
        const int n = lane + kk * 64;
        float v = (n < NOFF) ? dq[n] : INFINITY;
        if (n == SELF_IDX) v = -INFINITY;
        dv[kk] = v; dn[kk] = n;
    }
    int seln[KMAX];
    #pragma unroll
    for (int k = 0; k < KMAX; ++k) {
        float bv = dv[0]; int bi = dn[0];
        #pragma unroll
        for (int kk = 1; kk < 4; ++kk)
            if (dv[kk] < bv || (dv[kk] == bv && dn[kk] < bi)) { bv = dv[kk]; bi = dn[kk]; }
        #pragma unroll
        for (int off = 32; off > 0; off >>= 1) {
            const float ov = __shfl_xor(bv, off);
            const int   oi = __shfl_xor(bi, off);
            if (ov < bv || (ov == bv && oi < bi)) { bv = ov; bi = oi; }
        }
        seln[k] = bi;
        #pragma unroll
        for (int kk = 0; kk < 4; ++kk) if (dn[kk] == bi) dv[kk] = INFINITY;
    }

    // --- refine: deno-query vs noisy at selected positions (slots 1..k_eff-1) ---
    float part = 0.f;
    const int nref = (k_eff - 1) * 49;
    for (int u = lane; u < nref; u += 64) {
        const int kk = u / 49 + 1;
        const int ij = u - (kk - 1) * 49;
        const int i = ij / 7, j = ij - (ij / 7) * 7;
        int n = seln[1];
        #pragma unroll
        for (int t = 2; t < KMAX; ++t) if (kk == t) n = seln[t];
        const int dti = (n >= 162) ? 2 : (n >= 81 ? 1 : 0);
        const int rr  = n - dti * 81;
        const int dh  = rr / 9;
        const int dw  = rr - dh * 9;
        const int hcv = dti == 0 ? hv0 : (dti == 1 ? hv1 : hv2);
        const int wcv = dti == 0 ? wv0 : (dti == 1 ? wv1 : wv2);
        const int h0  = max(hcv - 4, 0), w0 = max(wcv - 4, 0);
        const int hc  = min(max(hcv + dh - 4, 0), HH - 1);
        const int wc  = min(max(wcv + dw - 4, 0), WW - 1);
        const int row = min(hc + i, HH - 1) - h0;
        const int col = min(wc + j, WW - 1) - w0;
        #pragma unroll
        for (int c = 0; c < CC; ++c) {
            const float d = dpat[wid][c][i][j] - tile[wid][dti][c][row][col];
            part = fmaf(d, d, part);
        }
    }

    #pragma unroll
    for (int off = 32; off > 0; off >>= 1) part += __shfl_xor(part, off);
    if (lane == 0) partial[q] = part;
}

__global__ __launch_bounds__(1024) void dnls_reduce_kernel(
    const float* __restrict__ partial, int n,
    const int* __restrict__ ep_ptr, float* __restrict__ out)
{
    const int tid = threadIdx.x;
    double acc = 0.0;
    for (int i = tid; i < n; i += 1024) acc += (double)partial[i];
    __shared__ double red[1024];
    red[tid] = acc;
    __syncthreads();
    for (int s = 512; s > 0; s >>= 1) {
        if (tid < s) red[tid] += red[tid + s];
        __syncthreads();
    }
    if (tid == 0) {
        const int k_eff = k_eff_from_epoch(ep_ptr[0]);
        out[0] = (float)(red[0] / ((double)n * (double)(k_eff - 1)));
    }
}

extern "C" void kernel_launch(void* const* d_in, const int* in_sizes, int n_in,
                              void* d_out, int out_size, void* d_ws, size_t ws_size,
                              hipStream_t stream) {
    const float* noisy = (const float*)d_in[0];
    const float* deno  = (const float*)d_in[1];
    const float* fflow = (const float*)d_in[2];
    const float* bflow = (const float*)d_in[3];
    const int*   ep    = (const int*)d_in[4];
    float* partial = (float*)d_ws;            // BB*QQ floats = 80 KB
    float* out = (float*)d_out;

    dnls_query_kernel<<<(BB * QQ) / 4, 256, 0, stream>>>(noisy, deno, fflow, bflow, ep, partial);
    dnls_reduce_kernel<<<1, 1024, 0, stream>>>(partial, BB * QQ, ep, out);
}